// Round 1
// baseline (714.716 us; speedup 1.0000x reference)
//
#include <hip/hip_runtime.h>
#include <hip/hip_bf16.h>

#define NN 100000
#define NE 3200000
#define NB_SCAN 98  // ceil(NN/1024)

static __device__ __forceinline__ float bf2f(unsigned short b) {
  union { unsigned int u; float f; } c; c.u = ((unsigned int)b) << 16; return c.f;
}
static __device__ __forceinline__ unsigned short f2bf(float f) {
  union { float f; unsigned int u; } c; c.f = f;
  unsigned int r = c.u + 0x7FFFu + ((c.u >> 16) & 1u);
  return (unsigned short)(r >> 16);
}

// ---------------- CSR build ----------------

__global__ __launch_bounds__(256) void k_hist(const int* __restrict__ row,
                                              int* __restrict__ cnt) {
  int i = blockIdx.x * 256 + threadIdx.x;
  if (i < NE) atomicAdd(&cnt[row[i]], 1);
}

__global__ __launch_bounds__(256) void k_scan_bsum(const int* __restrict__ cnt,
                                                   int* __restrict__ bsum) {
  __shared__ int sm[256];
  int t = threadIdx.x;
  int base = blockIdx.x * 1024 + t * 4;
  int s = 0;
#pragma unroll
  for (int j = 0; j < 4; ++j) {
    int idx = base + j;
    if (idx < NN) s += cnt[idx];
  }
  sm[t] = s;
  __syncthreads();
  for (int off = 128; off > 0; off >>= 1) {
    if (t < off) sm[t] += sm[t + off];
    __syncthreads();
  }
  if (t == 0) bsum[blockIdx.x] = sm[0];
}

__global__ __launch_bounds__(128) void k_scan_top(const int* __restrict__ bsum,
                                                  int* __restrict__ bpre) {
  __shared__ int sm[128];
  int t = threadIdx.x;
  int v = (t < NB_SCAN) ? bsum[t] : 0;
  sm[t] = v;
  __syncthreads();
  for (int off = 1; off < 128; off <<= 1) {
    int add = (t >= off) ? sm[t - off] : 0;
    __syncthreads();
    sm[t] += add;
    __syncthreads();
  }
  if (t < NB_SCAN) bpre[t] = sm[t] - v;  // exclusive
}

__global__ __launch_bounds__(256) void k_scan_final(const int* __restrict__ cnt,
                                                    const int* __restrict__ bpre,
                                                    int* __restrict__ rp,
                                                    int* __restrict__ wofs) {
  __shared__ int sm[256];
  int t = threadIdx.x;
  int base = blockIdx.x * 1024 + t * 4;
  int v[4];
  int s = 0;
#pragma unroll
  for (int j = 0; j < 4; ++j) {
    int idx = base + j;
    v[j] = (idx < NN) ? cnt[idx] : 0;
    s += v[j];
  }
  sm[t] = s;
  __syncthreads();
  for (int off = 1; off < 256; off <<= 1) {
    int add = (t >= off) ? sm[t - off] : 0;
    __syncthreads();
    sm[t] += add;
    __syncthreads();
  }
  int ex = sm[t] - s + bpre[blockIdx.x];  // exclusive across whole array
#pragma unroll
  for (int j = 0; j < 4; ++j) {
    int idx = base + j;
    if (idx < NN) { rp[idx] = ex; wofs[idx] = ex; }
    ex += v[j];
  }
  if (blockIdx.x == 0 && t == 0) rp[NN] = NE;
}

__global__ __launch_bounds__(256) void k_scatter(const int* __restrict__ row,
                                                 const int* __restrict__ col,
                                                 const float* __restrict__ val,
                                                 int* __restrict__ wofs,
                                                 float* __restrict__ val_s,
                                                 int* __restrict__ col_s) {
  int i = blockIdx.x * 256 + threadIdx.x;
  if (i < NE) {
    int r = row[i];
    int p = atomicAdd(&wofs[r], 1);
    val_s[p] = val[i];
    col_s[p] = col[i];
  }
}

// ---------------- dense layers (scalar-broadcast weights) ----------------

// h0 = bf16( 2 * (mask01(x) @ W0) + b0 ), one thread per row
__global__ __launch_bounds__(256) void k_gemm0(const float* __restrict__ x,
                                               const float* __restrict__ u,
                                               const float* __restrict__ W0,
                                               const float* __restrict__ b0,
                                               unsigned short* __restrict__ h0b) {
  int r = blockIdx.x * 256 + threadIdx.x;
  if (r >= NN) return;
  const float4* xr = (const float4*)(x + (size_t)r * 128);
  const float4* ur = (const float4*)(u + (size_t)r * 128);
  float acc[64];
#pragma unroll
  for (int d = 0; d < 64; ++d) acc[d] = 0.f;
#pragma unroll 1
  for (int kc = 0; kc < 8; ++kc) {
    float xm[16];
#pragma unroll
    for (int q = 0; q < 4; ++q) {
      float4 xv = xr[kc * 4 + q];
      float4 uv = ur[kc * 4 + q];
      xm[q * 4 + 0] = (uv.x >= 0.5f) ? xv.x : 0.f;
      xm[q * 4 + 1] = (uv.y >= 0.5f) ? xv.y : 0.f;
      xm[q * 4 + 2] = (uv.z >= 0.5f) ? xv.z : 0.f;
      xm[q * 4 + 3] = (uv.w >= 0.5f) ? xv.w : 0.f;
    }
#pragma unroll
    for (int k = 0; k < 16; ++k) {
      const float* wrow = W0 + (size_t)(kc * 16 + k) * 64;  // wave-uniform -> s_load
#pragma unroll
      for (int d = 0; d < 64; ++d) acc[d] = fmaf(xm[k], wrow[d], acc[d]);
    }
  }
  unsigned int* o32 = (unsigned int*)(h0b + (size_t)r * 64);
#pragma unroll
  for (int d = 0; d < 32; ++d) {
    float a = 2.f * acc[2 * d] + b0[2 * d];
    float b = 2.f * acc[2 * d + 1] + b0[2 * d + 1];
    o32[d] = (unsigned int)f2bf(a) | ((unsigned int)f2bf(b) << 16);
  }
}

// h1 = bf16( s1relu @ W1 + b1 ), one thread per row (s1b already relu'd)
__global__ __launch_bounds__(256) void k_gemm1(const unsigned short* __restrict__ s1b,
                                               const float* __restrict__ W1,
                                               const float* __restrict__ b1,
                                               unsigned short* __restrict__ h1b) {
  int r = blockIdx.x * 256 + threadIdx.x;
  if (r >= NN) return;
  const uint4* sr = (const uint4*)(s1b + (size_t)r * 64);
  float acc[32];
#pragma unroll
  for (int d = 0; d < 32; ++d) acc[d] = 0.f;
#pragma unroll 1
  for (int kc = 0; kc < 4; ++kc) {
    uint4 w0 = sr[2 * kc], w1 = sr[2 * kc + 1];
    unsigned int wsv[8] = {w0.x, w0.y, w0.z, w0.w, w1.x, w1.y, w1.z, w1.w};
    float s[16];
#pragma unroll
    for (int q = 0; q < 8; ++q) {
      union { unsigned int u; float f; } lo, hi;
      lo.u = wsv[q] << 16;
      hi.u = wsv[q] & 0xFFFF0000u;
      s[2 * q] = lo.f;
      s[2 * q + 1] = hi.f;
    }
#pragma unroll
    for (int k = 0; k < 16; ++k) {
      const float* wrow = W1 + (size_t)(kc * 16 + k) * 32;  // wave-uniform -> s_load
#pragma unroll
      for (int d = 0; d < 32; ++d) acc[d] = fmaf(s[k], wrow[d], acc[d]);
    }
  }
  unsigned int* o32 = (unsigned int*)(h1b + (size_t)r * 32);
#pragma unroll
  for (int d = 0; d < 16; ++d) {
    float a = acc[2 * d] + b1[2 * d];
    float b = acc[2 * d + 1] + b1[2 * d + 1];
    o32[d] = (unsigned int)f2bf(a) | ((unsigned int)f2bf(b) << 16);
  }
}

// ---------------- SpMM (CSR gather, wave per row) ----------------

// s1b[r][d] = relu( sum_j val_s[j] * h0b[col_s[j]][d] ), D=64, lane=d
__global__ __launch_bounds__(256) void k_spmm1(const int* __restrict__ rp,
                                               const float* __restrict__ val_s,
                                               const int* __restrict__ col_s,
                                               const unsigned short* __restrict__ h0b,
                                               unsigned short* __restrict__ s1b) {
  int wid = (blockIdx.x * 256 + threadIdx.x) >> 6;
  int lane = threadIdx.x & 63;
  if (wid >= NN) return;
  int j0 = rp[wid], j1 = rp[wid + 1];
  float acc = 0.f;
#pragma unroll 4
  for (int j = j0; j < j1; ++j) {
    float v = val_s[j];
    int c = col_s[j];
    acc = fmaf(v, bf2f(h0b[(size_t)c * 64 + lane]), acc);
  }
  s1b[(size_t)wid * 64 + lane] = f2bf(fmaxf(acc, 0.f));
}

// out[r][d] = sum_j val_s[j] * h1b[col_s[j]][d], D=32, two edges in parallel per wave
__global__ __launch_bounds__(256) void k_spmm2(const int* __restrict__ rp,
                                               const float* __restrict__ val_s,
                                               const int* __restrict__ col_s,
                                               const unsigned short* __restrict__ h1b,
                                               float* __restrict__ out) {
  int wid = (blockIdx.x * 256 + threadIdx.x) >> 6;
  int lane = threadIdx.x & 63;
  if (wid >= NN) return;
  int h = lane >> 5, d = lane & 31;
  int j0 = rp[wid], j1 = rp[wid + 1];
  float acc = 0.f;
#pragma unroll 2
  for (int j = j0 + h; j < j1; j += 2) {
    float v = val_s[j];
    int c = col_s[j];
    acc = fmaf(v, bf2f(h1b[(size_t)c * 32 + d]), acc);
  }
  acc += __shfl_xor(acc, 32);
  if (h == 0) out[(size_t)wid * 32 + d] = acc;
}

// ---------------- launch ----------------

extern "C" void kernel_launch(void* const* d_in, const int* in_sizes, int n_in,
                              void* d_out, int out_size, void* d_ws, size_t ws_size,
                              hipStream_t stream) {
  const float* x   = (const float*)d_in[0];
  const float* u   = (const float*)d_in[1];
  const float* val = (const float*)d_in[2];
  const int* row   = (const int*)d_in[3];
  const int* col   = (const int*)d_in[4];
  const float* W0  = (const float*)d_in[5];
  const float* b0  = (const float*)d_in[6];
  const float* W1  = (const float*)d_in[7];
  const float* b1  = (const float*)d_in[8];
  float* out = (float*)d_out;

  char* p = (char*)d_ws;
  auto take = [&](size_t bytes) {
    char* q = p;
    p += (bytes + 255) & ~(size_t)255;
    return q;
  };
  unsigned short* h0b = (unsigned short*)take((size_t)NN * 64 * 2);
  unsigned short* s1b = (unsigned short*)take((size_t)NN * 64 * 2);
  unsigned short* h1b = (unsigned short*)take((size_t)NN * 32 * 2);
  float* val_s = (float*)take((size_t)NE * 4);
  int* col_s   = (int*)take((size_t)NE * 4);
  int* cnt  = (int*)take((size_t)NN * 4);
  int* rp   = (int*)take((size_t)(NN + 1) * 4);
  int* wofs = (int*)take((size_t)NN * 4);
  int* bsum = (int*)take(1024);
  int* bpre = (int*)take(1024);

  // CSR build
  hipMemsetAsync(cnt, 0, (size_t)NN * 4, stream);
  k_hist<<<NE / 256, 256, 0, stream>>>(row, cnt);
  k_scan_bsum<<<NB_SCAN, 256, 0, stream>>>(cnt, bsum);
  k_scan_top<<<1, 128, 0, stream>>>(bsum, bpre);
  k_scan_final<<<NB_SCAN, 256, 0, stream>>>(cnt, bpre, rp, wofs);
  k_scatter<<<NE / 256, 256, 0, stream>>>(row, col, val, wofs, val_s, col_s);

  // dense + sparse pipeline
  k_gemm0<<<(NN + 255) / 256, 256, 0, stream>>>(x, u, W0, b0, h0b);
  k_spmm1<<<NN / 4, 256, 0, stream>>>(rp, val_s, col_s, h0b, s1b);
  k_gemm1<<<(NN + 255) / 256, 256, 0, stream>>>(s1b, W1, b1, h1b);
  k_spmm2<<<NN / 4, 256, 0, stream>>>(rp, val_s, col_s, h1b, out);
}

// Round 2
// 409.296 us; speedup vs baseline: 1.7462x; 1.7462x over previous
//
#include <hip/hip_runtime.h>

#define NN 100000
#define NE 3200000
#define EB 8192            // edges per partition block
#define NBP 391            // ceil(NE/EB)
#define BSH 9              // bucket = row >> 9
#define BRW 512            // rows per bucket
#define NBK 196            // ceil(NN/BRW)

static __device__ __forceinline__ float bf2f(unsigned short b) {
  union { unsigned int u; float f; } c; c.u = ((unsigned int)b) << 16; return c.f;
}
static __device__ __forceinline__ unsigned short f2bf(float f) {
  union { float f; unsigned int u; } c; c.f = f;
  unsigned int r = c.u + 0x7FFFu + ((c.u >> 16) & 1u);
  return (unsigned short)(r >> 16);
}

// ---------------- CSR build: two-level bucket sort ----------------

__global__ __launch_bounds__(256) void k_phist(const int* __restrict__ row,
                                               int* __restrict__ bcnt) {
  __shared__ int h[NBK];
  int t = threadIdx.x;
  if (t < NBK) h[t] = 0;
  __syncthreads();
  int e0 = blockIdx.x * EB;
  int n = min(EB, NE - e0);
  for (int i = t; i < n; i += 256) atomicAdd(&h[row[e0 + i] >> BSH], 1);
  __syncthreads();
  if (t < NBK && h[t]) atomicAdd(&bcnt[t], h[t]);
}

__global__ __launch_bounds__(256) void k_bscan(const int* __restrict__ bcnt,
                                               int* __restrict__ bbase,
                                               int* __restrict__ bcur) {
  __shared__ int s[256];
  int t = threadIdx.x;
  int v = (t < NBK) ? bcnt[t] : 0;
  s[t] = v;
  __syncthreads();
  for (int off = 1; off < 256; off <<= 1) {
    int a = (t >= off) ? s[t - off] : 0;
    __syncthreads();
    s[t] += a;
    __syncthreads();
  }
  int ex = s[t] - v;
  if (t < NBK) { bbase[t] = ex; bcur[t] = ex; }
  if (t == NBK - 1) bbase[NBK] = ex + v;  // == NE
}

// partition edges into bucket-contiguous tmp[], LDS-staged for coalesced writes
__global__ __launch_bounds__(256) void k_part(const int* __restrict__ row,
                                              const int* __restrict__ col,
                                              const float* __restrict__ val,
                                              int* __restrict__ bcur,
                                              uint2* __restrict__ tmp) {
  __shared__ uint2 stage[EB];   // 64 KB
  __shared__ int dst[EB];       // 32 KB
  __shared__ int h[NBK];
  __shared__ int bex[NBK];
  __shared__ int win[NBK];
  __shared__ int c2[NBK];
  __shared__ int sc[256];
  int t = threadIdx.x;
  int e0 = blockIdx.x * EB;
  int n = min(EB, NE - e0);
  if (t < NBK) { h[t] = 0; c2[t] = 0; }
  __syncthreads();
  for (int i = t; i < n; i += 256) atomicAdd(&h[row[e0 + i] >> BSH], 1);
  __syncthreads();
  int v = (t < NBK) ? h[t] : 0;
  sc[t] = v;
  __syncthreads();
  for (int off = 1; off < 256; off <<= 1) {
    int a = (t >= off) ? sc[t - off] : 0;
    __syncthreads();
    sc[t] += a;
    __syncthreads();
  }
  int ex = sc[t] - v;
  if (t < NBK) {
    bex[t] = ex;
    win[t] = v ? atomicAdd(&bcur[t], v) : 0;
  }
  __syncthreads();
  for (int i = t; i < n; i += 256) {
    int e = e0 + i;
    int r = row[e];
    unsigned int c = (unsigned int)col[e];
    float vv = val[e];
    int b = r >> BSH;
    int rank = atomicAdd(&c2[b], 1);
    int s_ = bex[b] + rank;
    uint2 w;
    w.x = __float_as_uint(vv);
    w.y = ((unsigned int)(r & (BRW - 1)) << 17) | c;
    stage[s_] = w;
    dst[s_] = win[b] + rank;
  }
  __syncthreads();
  for (int i = t; i < n; i += 256) tmp[dst[i]] = stage[i];
}

// per-bucket counting sort by row -> final CSR (vc packed) + row pointers
__global__ __launch_bounds__(512) void k_bsort(const int* __restrict__ bbase,
                                               const uint2* __restrict__ tmp,
                                               uint2* __restrict__ vc,
                                               int* __restrict__ rp) {
  __shared__ int cnt[BRW];
  __shared__ int pre[BRW];
  __shared__ int c2[BRW];
  int t = threadIdx.x;
  int b = blockIdx.x;
  int s0 = bbase[b], s1 = bbase[b + 1];
  int n = s1 - s0;
  cnt[t] = 0; c2[t] = 0;
  __syncthreads();
  for (int i = t; i < n; i += 512) atomicAdd(&cnt[tmp[s0 + i].y >> 17], 1);
  __syncthreads();
  int v = cnt[t];
  pre[t] = v;
  __syncthreads();
  for (int off = 1; off < 512; off <<= 1) {
    int a = (t >= off) ? pre[t - off] : 0;
    __syncthreads();
    pre[t] += a;
    __syncthreads();
  }
  int ex = pre[t] - v;
  int r = (b << BSH) + t;
  if (r < NN) rp[r] = s0 + ex;
  if (b == NBK - 1 && t == 0) rp[NN] = NE;
  pre[t] = ex;
  __syncthreads();
  for (int i = t; i < n; i += 512) {
    uint2 w = tmp[s0 + i];
    int rl = (int)(w.y >> 17);
    int rank = atomicAdd(&c2[rl], 1);
    int pos = s0 + pre[rl] + rank;
    uint2 o;
    o.x = w.x;
    o.y = w.y & 0x1FFFFu;
    vc[pos] = o;
  }
}

// ---------------- dense layers (scalar-broadcast weights) ----------------

__global__ __launch_bounds__(256) void k_gemm0(const float* __restrict__ x,
                                               const float* __restrict__ u,
                                               const float* __restrict__ W0,
                                               const float* __restrict__ b0,
                                               unsigned short* __restrict__ h0b) {
  int r = blockIdx.x * 256 + threadIdx.x;
  if (r >= NN) return;
  const float4* xr = (const float4*)(x + (size_t)r * 128);
  const float4* ur = (const float4*)(u + (size_t)r * 128);
  float acc[64];
#pragma unroll
  for (int d = 0; d < 64; ++d) acc[d] = 0.f;
#pragma unroll 1
  for (int kc = 0; kc < 8; ++kc) {
    float xm[16];
#pragma unroll
    for (int q = 0; q < 4; ++q) {
      float4 xv = xr[kc * 4 + q];
      float4 uv = ur[kc * 4 + q];
      xm[q * 4 + 0] = (uv.x >= 0.5f) ? xv.x : 0.f;
      xm[q * 4 + 1] = (uv.y >= 0.5f) ? xv.y : 0.f;
      xm[q * 4 + 2] = (uv.z >= 0.5f) ? xv.z : 0.f;
      xm[q * 4 + 3] = (uv.w >= 0.5f) ? xv.w : 0.f;
    }
#pragma unroll
    for (int k = 0; k < 16; ++k) {
      const float* wrow = W0 + (size_t)(kc * 16 + k) * 64;  // wave-uniform -> s_load
#pragma unroll
      for (int d = 0; d < 64; ++d) acc[d] = fmaf(xm[k], wrow[d], acc[d]);
    }
  }
  unsigned int* o32 = (unsigned int*)(h0b + (size_t)r * 64);
#pragma unroll
  for (int d = 0; d < 32; ++d) {
    float a = 2.f * acc[2 * d] + b0[2 * d];
    float b = 2.f * acc[2 * d + 1] + b0[2 * d + 1];
    o32[d] = (unsigned int)f2bf(a) | ((unsigned int)f2bf(b) << 16);
  }
}

__global__ __launch_bounds__(256) void k_gemm1(const unsigned short* __restrict__ s1b,
                                               const float* __restrict__ W1,
                                               const float* __restrict__ b1,
                                               unsigned short* __restrict__ h1b) {
  int r = blockIdx.x * 256 + threadIdx.x;
  if (r >= NN) return;
  const uint4* sr = (const uint4*)(s1b + (size_t)r * 64);
  float acc[32];
#pragma unroll
  for (int d = 0; d < 32; ++d) acc[d] = 0.f;
#pragma unroll 1
  for (int kc = 0; kc < 4; ++kc) {
    uint4 w0 = sr[2 * kc], w1 = sr[2 * kc + 1];
    unsigned int wsv[8] = {w0.x, w0.y, w0.z, w0.w, w1.x, w1.y, w1.z, w1.w};
    float s[16];
#pragma unroll
    for (int q = 0; q < 8; ++q) {
      union { unsigned int u; float f; } lo, hi;
      lo.u = wsv[q] << 16;
      hi.u = wsv[q] & 0xFFFF0000u;
      s[2 * q] = lo.f;
      s[2 * q + 1] = hi.f;
    }
#pragma unroll
    for (int k = 0; k < 16; ++k) {
      const float* wrow = W1 + (size_t)(kc * 16 + k) * 32;  // wave-uniform -> s_load
#pragma unroll
      for (int d = 0; d < 32; ++d) acc[d] = fmaf(s[k], wrow[d], acc[d]);
    }
  }
  unsigned int* o32 = (unsigned int*)(h1b + (size_t)r * 32);
#pragma unroll
  for (int d = 0; d < 16; ++d) {
    float a = acc[2 * d] + b1[2 * d];
    float b = acc[2 * d + 1] + b1[2 * d + 1];
    o32[d] = (unsigned int)f2bf(a) | ((unsigned int)f2bf(b) << 16);
  }
}

// ---------------- SpMM (CSR gather, wave per row) ----------------

__global__ __launch_bounds__(256) void k_spmm1(const int* __restrict__ rp,
                                               const uint2* __restrict__ vc,
                                               const unsigned short* __restrict__ h0b,
                                               unsigned short* __restrict__ s1b) {
  int wid = (blockIdx.x * 256 + threadIdx.x) >> 6;
  int lane = threadIdx.x & 63;
  if (wid >= NN) return;
  int j0 = rp[wid], j1 = rp[wid + 1];
  float acc = 0.f;
  int j = j0;
  for (; j + 4 <= j1; j += 4) {
    uint2 w0 = vc[j], w1 = vc[j + 1], w2 = vc[j + 2], w3 = vc[j + 3];
    float f0 = bf2f(h0b[(size_t)w0.y * 64 + lane]);
    float f1 = bf2f(h0b[(size_t)w1.y * 64 + lane]);
    float f2 = bf2f(h0b[(size_t)w2.y * 64 + lane]);
    float f3 = bf2f(h0b[(size_t)w3.y * 64 + lane]);
    acc = fmaf(__uint_as_float(w0.x), f0, acc);
    acc = fmaf(__uint_as_float(w1.x), f1, acc);
    acc = fmaf(__uint_as_float(w2.x), f2, acc);
    acc = fmaf(__uint_as_float(w3.x), f3, acc);
  }
  for (; j < j1; ++j) {
    uint2 w = vc[j];
    acc = fmaf(__uint_as_float(w.x), bf2f(h0b[(size_t)w.y * 64 + lane]), acc);
  }
  s1b[(size_t)wid * 64 + lane] = f2bf(fmaxf(acc, 0.f));
}

__global__ __launch_bounds__(256) void k_spmm2(const int* __restrict__ rp,
                                               const uint2* __restrict__ vc,
                                               const unsigned short* __restrict__ h1b,
                                               float* __restrict__ out) {
  int wid = (blockIdx.x * 256 + threadIdx.x) >> 6;
  int lane = threadIdx.x & 63;
  if (wid >= NN) return;
  int h = lane >> 5, d = lane & 31;
  int j0 = rp[wid], j1 = rp[wid + 1];
  float acc = 0.f;
  int j = j0 + h;
  for (; j + 2 < j1; j += 4) {
    uint2 w0 = vc[j], w1 = vc[j + 2];
    float f0 = bf2f(h1b[(size_t)w0.y * 32 + d]);
    float f1 = bf2f(h1b[(size_t)w1.y * 32 + d]);
    acc = fmaf(__uint_as_float(w0.x), f0, acc);
    acc = fmaf(__uint_as_float(w1.x), f1, acc);
  }
  for (; j < j1; j += 2) {
    uint2 w = vc[j];
    acc = fmaf(__uint_as_float(w.x), bf2f(h1b[(size_t)w.y * 32 + d]), acc);
  }
  acc += __shfl_xor(acc, 32);
  if (h == 0) out[(size_t)wid * 32 + d] = acc;
}

// ---------------- launch ----------------

extern "C" void kernel_launch(void* const* d_in, const int* in_sizes, int n_in,
                              void* d_out, int out_size, void* d_ws, size_t ws_size,
                              hipStream_t stream) {
  const float* x   = (const float*)d_in[0];
  const float* u   = (const float*)d_in[1];
  const float* val = (const float*)d_in[2];
  const int* row   = (const int*)d_in[3];
  const int* col   = (const int*)d_in[4];
  const float* W0  = (const float*)d_in[5];
  const float* b0  = (const float*)d_in[6];
  const float* W1  = (const float*)d_in[7];
  const float* b1  = (const float*)d_in[8];
  float* out = (float*)d_out;

  char* p = (char*)d_ws;
  auto take = [&](size_t bytes) {
    char* q = p;
    p += (bytes + 255) & ~(size_t)255;
    return q;
  };
  uint2* tmp = (uint2*)take((size_t)NE * 8);          // dead after k_bsort
  uint2* vc  = (uint2*)take((size_t)NE * 8);
  unsigned short* s1b = (unsigned short*)take((size_t)NN * 64 * 2);
  int* rp    = (int*)take((size_t)(NN + 1) * 4);
  int* bcnt  = (int*)take((size_t)NBK * 4);
  int* bbase = (int*)take((size_t)(NBK + 1) * 4);
  int* bcur  = (int*)take((size_t)NBK * 4);
  // alias h0b (12.8 MB) and h1b (6.4 MB) into tmp's 25.6 MB (tmp dead by gemm0)
  unsigned short* h0b = (unsigned short*)tmp;
  unsigned short* h1b = (unsigned short*)((char*)tmp + (size_t)NN * 64 * 2);

  // CSR build (bucketed two-level sort)
  hipMemsetAsync(bcnt, 0, (size_t)NBK * 4, stream);
  k_phist<<<NBP, 256, 0, stream>>>(row, bcnt);
  k_bscan<<<1, 256, 0, stream>>>(bcnt, bbase, bcur);
  k_part<<<NBP, 256, 0, stream>>>(row, col, val, bcur, tmp);
  k_bsort<<<NBK, 512, 0, stream>>>(bbase, tmp, vc, rp);

  // dense + sparse pipeline
  k_gemm0<<<(NN + 255) / 256, 256, 0, stream>>>(x, u, W0, b0, h0b);
  k_spmm1<<<(NN + 3) / 4, 256, 0, stream>>>(rp, vc, h0b, s1b);
  k_gemm1<<<(NN + 255) / 256, 256, 0, stream>>>(s1b, W1, b1, h1b);
  k_spmm2<<<(NN + 3) / 4, 256, 0, stream>>>(rp, vc, h1b, out);
}